// Round 1
// baseline (137.533 us; speedup 1.0000x reference)
//
#include <hip/hip_runtime.h>

typedef unsigned short u16;
typedef u16 u16x8 __attribute__((ext_vector_type(8)));
typedef __bf16 bf16x8 __attribute__((ext_vector_type(8)));
typedef float f32x4 __attribute__((ext_vector_type(4)));

#define MFMA16 __builtin_amdgcn_mfma_f32_16x16x32_bf16

// fp32 -> bf16 round-to-nearest-even
__device__ __forceinline__ u16 f2bf(float f) {
  unsigned u = __builtin_bit_cast(unsigned, f);
  u += 0x7FFFu + ((u >> 16) & 1u);
  return (u16)(u >> 16);
}

// XOR-swizzled LDS byte address for 64-bf16 (128B) rows: kills the 16-way
// ds_read_b128 bank conflict (guide G4).
__device__ __forceinline__ int swz(int row, int bcol) {
  return row * 128 + (bcol ^ ((row & 7) << 4));
}

// ---------------------------------------------------------------------------
// QKV projection: C = X @ W^T + b, written as bf16 into [B,H,S,64] layout.
// grid (8, 32, 3): x = N-tile, y = M-tile, z selects q/k/v.
// 128x128 tile, BK=64, 4 waves (2x2), 16x16x32 bf16 MFMA.
// ---------------------------------------------------------------------------
__global__ __launch_bounds__(256)
void qkv_gemm(const float* __restrict__ x0, const float* __restrict__ x1,
              const float* __restrict__ x2, const float* __restrict__ w0,
              const float* __restrict__ w1, const float* __restrict__ w2,
              const float* __restrict__ c0, const float* __restrict__ c1,
              const float* __restrict__ c2, u16* __restrict__ o0,
              u16* __restrict__ o1, u16* __restrict__ o2) {
  const int z = blockIdx.z;
  const float* X = (z == 0) ? x0 : (z == 1) ? x1 : x2;
  const float* W = (z == 0) ? w0 : (z == 1) ? w1 : w2;
  const float* Bi = (z == 0) ? c0 : (z == 1) ? c1 : c2;
  u16* O = (z == 0) ? o0 : (z == 1) ? o1 : o2;

  const int m0 = blockIdx.y * 128, n0 = blockIdx.x * 128;
  const int tid = threadIdx.x, lane = tid & 63, w = tid >> 6;
  const int wr = w >> 1, wc = w & 1;
  const int r = lane & 15, g = lane >> 4;
  const int srow = tid >> 3, sc = (tid & 7) * 8;

  __shared__ u16 As[128 * 64];
  __shared__ u16 Bs[128 * 64];

  f32x4 acc[4][4] = {};

  for (int kt = 0; kt < 16; ++kt) {
    __syncthreads();
#pragma unroll
    for (int i = 0; i < 4; ++i) {
      int row = i * 32 + srow;
      const float* ga = X + (m0 + row) * 1024 + kt * 64 + sc;
      float4 a0 = *(const float4*)ga, a1 = *(const float4*)(ga + 4);
      u16x8 pa = {f2bf(a0.x), f2bf(a0.y), f2bf(a0.z), f2bf(a0.w),
                  f2bf(a1.x), f2bf(a1.y), f2bf(a1.z), f2bf(a1.w)};
      *(u16x8*)((char*)As + swz(row, sc * 2)) = pa;
      const float* gb = W + (n0 + row) * 1024 + kt * 64 + sc;
      float4 b0v = *(const float4*)gb, b1v = *(const float4*)(gb + 4);
      u16x8 pb = {f2bf(b0v.x), f2bf(b0v.y), f2bf(b0v.z), f2bf(b0v.w),
                  f2bf(b1v.x), f2bf(b1v.y), f2bf(b1v.z), f2bf(b1v.w)};
      *(u16x8*)((char*)Bs + swz(row, sc * 2)) = pb;
    }
    __syncthreads();
#pragma unroll
    for (int kk = 0; kk < 2; ++kk) {
      bf16x8 af[4], bfr[4];
#pragma unroll
      for (int m = 0; m < 4; ++m)
        af[m] = __builtin_bit_cast(
            bf16x8, *(const u16x8*)((char*)As +
                                    swz(wr * 64 + m * 16 + r, kk * 64 + g * 16)));
#pragma unroll
      for (int n = 0; n < 4; ++n)
        bfr[n] = __builtin_bit_cast(
            bf16x8, *(const u16x8*)((char*)Bs +
                                    swz(wc * 64 + n * 16 + r, kk * 64 + g * 16)));
#pragma unroll
      for (int m = 0; m < 4; ++m)
#pragma unroll
        for (int n = 0; n < 4; ++n)
          acc[m][n] = MFMA16(af[m], bfr[n], acc[m][n], 0, 0, 0);
    }
  }

  // epilogue: C[gm][gn] -> bf16 [B,H,S,64]; C/D layout col=lane&15, row=g*4+q
#pragma unroll
  for (int m = 0; m < 4; ++m) {
#pragma unroll
    for (int n = 0; n < 4; ++n) {
      int gn = n0 + wc * 64 + n * 16 + r;
      int hh = gn >> 6, d = gn & 63;
      float bv = Bi[gn];
#pragma unroll
      for (int q = 0; q < 4; ++q) {
        int gm = m0 + wr * 64 + m * 16 + g * 4 + q;
        int bb = gm >> 11, s = gm & 2047;
        O[((bb * 16 + hh) * 2048 + s) * 64 + d] = f2bf(acc[m][n][q] + bv);
      }
    }
  }
}

// ---------------------------------------------------------------------------
// Output projection: C = A(bf16) @ W^T + b, fp32 out.
// ---------------------------------------------------------------------------
__global__ __launch_bounds__(256)
void out_gemm(const u16* __restrict__ A, const float* __restrict__ W,
              const float* __restrict__ Bi, float* __restrict__ C) {
  const int m0 = blockIdx.y * 128, n0 = blockIdx.x * 128;
  const int tid = threadIdx.x, lane = tid & 63, w = tid >> 6;
  const int wr = w >> 1, wc = w & 1;
  const int r = lane & 15, g = lane >> 4;
  const int srow = tid >> 3, sc = (tid & 7) * 8;

  __shared__ u16 As[128 * 64];
  __shared__ u16 Bs[128 * 64];

  f32x4 acc[4][4] = {};

  for (int kt = 0; kt < 16; ++kt) {
    __syncthreads();
#pragma unroll
    for (int i = 0; i < 4; ++i) {
      int row = i * 32 + srow;
      u16x8 pa = *(const u16x8*)(A + (m0 + row) * 1024 + kt * 64 + sc);
      *(u16x8*)((char*)As + swz(row, sc * 2)) = pa;
      const float* gb = W + (n0 + row) * 1024 + kt * 64 + sc;
      float4 b0v = *(const float4*)gb, b1v = *(const float4*)(gb + 4);
      u16x8 pb = {f2bf(b0v.x), f2bf(b0v.y), f2bf(b0v.z), f2bf(b0v.w),
                  f2bf(b1v.x), f2bf(b1v.y), f2bf(b1v.z), f2bf(b1v.w)};
      *(u16x8*)((char*)Bs + swz(row, sc * 2)) = pb;
    }
    __syncthreads();
#pragma unroll
    for (int kk = 0; kk < 2; ++kk) {
      bf16x8 af[4], bfr[4];
#pragma unroll
      for (int m = 0; m < 4; ++m)
        af[m] = __builtin_bit_cast(
            bf16x8, *(const u16x8*)((char*)As +
                                    swz(wr * 64 + m * 16 + r, kk * 64 + g * 16)));
#pragma unroll
      for (int n = 0; n < 4; ++n)
        bfr[n] = __builtin_bit_cast(
            bf16x8, *(const u16x8*)((char*)Bs +
                                    swz(wc * 64 + n * 16 + r, kk * 64 + g * 16)));
#pragma unroll
      for (int m = 0; m < 4; ++m)
#pragma unroll
        for (int n = 0; n < 4; ++n)
          acc[m][n] = MFMA16(af[m], bfr[n], acc[m][n], 0, 0, 0);
    }
  }

#pragma unroll
  for (int m = 0; m < 4; ++m) {
#pragma unroll
    for (int n = 0; n < 4; ++n) {
      int gn = n0 + wc * 64 + n * 16 + r;
      float bv = Bi[gn];
#pragma unroll
      for (int q = 0; q < 4; ++q) {
        int gm = m0 + wr * 64 + m * 16 + g * 4 + q;
        C[gm * 1024 + gn] = acc[m][n][q] + bv;
      }
    }
  }
}

// ---------------------------------------------------------------------------
// Sparse flash attention. grid (32 qtiles, 16 heads, 2 batch), 256 threads.
// Q-tile = 64 rows (16 per wave), KV-tile = 64. Tiles needed per q-tile k:
// {0} ∪ {k-2, k-1, k} (global-16 lives in tile 0; local window 128 spans 2
// tiles back). Mask: (j<=i) && (i-j<=128 || j<16). Online softmax, fp32 state.
// ---------------------------------------------------------------------------
__global__ __launch_bounds__(256)
void attn_kernel(const u16* __restrict__ Q, const u16* __restrict__ K,
                 const u16* __restrict__ V, u16* __restrict__ O) {
  const int qt = blockIdx.x, h = blockIdx.y, b = blockIdx.z;
  const int tid = threadIdx.x, lane = tid & 63, w = tid >> 6;
  const int r = lane & 15, g = lane >> 4;
  const int q0 = qt * 64;
  const int base = (b * 16 + h) * 131072;  // 2048*64
  const u16* Qb = Q + base;
  const u16* Kb = K + base;
  const u16* Vb = V + base;

  __shared__ u16 Ks[64 * 64];
  __shared__ u16 Vt[64 * 64];   // transposed: Vt[d][j]
  __shared__ u16 Pl[4608];      // 4 waves x 16 rows x 144B stride

  // Q fragments in registers: lane holds Q[q0+w*16+r][g*8 .. g*8+7] (+32 for kk=1)
  bf16x8 qf[2];
  {
    const u16* qp = Qb + (q0 + w * 16 + r) * 64 + g * 8;
    qf[0] = __builtin_bit_cast(bf16x8, *(const u16x8*)qp);
    qf[1] = __builtin_bit_cast(bf16x8, *(const u16x8*)(qp + 32));
  }

  f32x4 acc[4] = {};
  float m_run[4] = {-1e30f, -1e30f, -1e30f, -1e30f};
  float l_run[4] = {};

  const int nt = (qt <= 3) ? (qt + 1) : 4;
  const int srow = tid >> 3, sc = (tid & 7) * 8;

  for (int tix = 0; tix < nt; ++tix) {
    const int t = (tix == 0) ? 0 : ((qt <= 3) ? tix : (qt - 3 + tix));
    const int j0 = t * 64;
    __syncthreads();
    // stage K (swizzled row-major) and V (transposed, swizzled)
#pragma unroll
    for (int i = 0; i < 2; ++i) {
      int row = i * 32 + srow;
      u16x8 kv = *(const u16x8*)(Kb + (j0 + row) * 64 + sc);
      *(u16x8*)((char*)Ks + swz(row, sc * 2)) = kv;
      u16x8 vv = *(const u16x8*)(Vb + (j0 + row) * 64 + sc);
#pragma unroll
      for (int qq = 0; qq < 8; ++qq) {
        int d = sc + qq;
        *(u16*)((char*)Vt + d * 128 + ((2 * row) ^ ((d & 7) << 4))) = vv[qq];
      }
    }
    __syncthreads();

    // S = Q K^T
    f32x4 S[4] = {};
#pragma unroll
    for (int kk = 0; kk < 2; ++kk)
#pragma unroll
      for (int n = 0; n < 4; ++n) {
        bf16x8 kf = __builtin_bit_cast(
            bf16x8,
            *(const u16x8*)((char*)Ks + swz(n * 16 + r, kk * 64 + g * 16)));
        S[n] = MFMA16(qf[kk], kf, S[n], 0, 0, 0);
      }

    // scale + mask + row max
    float mloc[4] = {-1e30f, -1e30f, -1e30f, -1e30f};
#pragma unroll
    for (int n = 0; n < 4; ++n) {
      int j = j0 + n * 16 + r;
#pragma unroll
      for (int q = 0; q < 4; ++q) {
        int i = q0 + w * 16 + g * 4 + q;
        bool ok = (j <= i) && (((i - j) <= 128) || (j < 16));
        float s = ok ? S[n][q] * 0.125f : -1e30f;
        S[n][q] = s;
        mloc[q] = fmaxf(mloc[q], s);
      }
    }
#pragma unroll
    for (int q = 0; q < 4; ++q)
#pragma unroll
      for (int off = 1; off < 16; off <<= 1)
        mloc[q] = fmaxf(mloc[q], __shfl_xor(mloc[q], off));

    float alpha[4], rsum[4] = {};
#pragma unroll
    for (int q = 0; q < 4; ++q) {
      float mn = fmaxf(m_run[q], mloc[q]);
      alpha[q] = __expf(m_run[q] - mn);
      m_run[q] = mn;
    }
#pragma unroll
    for (int n = 0; n < 4; ++n)
#pragma unroll
      for (int q = 0; q < 4; ++q) {
        float p = __expf(S[n][q] - m_run[q]);
        S[n][q] = p;
        rsum[q] += p;
      }
#pragma unroll
    for (int q = 0; q < 4; ++q) {
#pragma unroll
      for (int off = 1; off < 16; off <<= 1)
        rsum[q] += __shfl_xor(rsum[q], off);
      l_run[q] = l_run[q] * alpha[q] + rsum[q];
    }
#pragma unroll
    for (int n = 0; n < 4; ++n) {
      acc[n][0] *= alpha[0];
      acc[n][1] *= alpha[1];
      acc[n][2] *= alpha[2];
      acc[n][3] *= alpha[3];
    }

    // P (bf16) -> per-wave LDS in MFMA-A layout staging buffer
#pragma unroll
    for (int n = 0; n < 4; ++n)
#pragma unroll
      for (int q = 0; q < 4; ++q)
        *((u16*)((char*)Pl + w * 2304 + (g * 4 + q) * 144) + (n * 16 + r)) =
            f2bf(S[n][q]);

    // O += P V  (A = P from Pl, B = V from transposed Vt)
#pragma unroll
    for (int kk = 0; kk < 2; ++kk) {
      bf16x8 pf = __builtin_bit_cast(
          bf16x8,
          *(const u16x8*)((char*)Pl + w * 2304 + r * 144 + kk * 64 + g * 16));
#pragma unroll
      for (int n = 0; n < 4; ++n) {
        bf16x8 vf = __builtin_bit_cast(
            bf16x8,
            *(const u16x8*)((char*)Vt + swz(n * 16 + r, kk * 64 + g * 16)));
        acc[n] = MFMA16(pf, vf, acc[n], 0, 0, 0);
      }
    }
  }

  // epilogue: divide by softmax denom, write bf16 [B,S,H*64]
#pragma unroll
  for (int n = 0; n < 4; ++n)
#pragma unroll
    for (int q = 0; q < 4; ++q) {
      int s = q0 + w * 16 + g * 4 + q;
      int d = n * 16 + r;
      O[(b * 2048 + s) * 1024 + h * 64 + d] = f2bf(acc[n][q] / l_run[q]);
    }
}

// ---------------------------------------------------------------------------
extern "C" void kernel_launch(void* const* d_in, const int* in_sizes, int n_in,
                              void* d_out, int out_size, void* d_ws,
                              size_t ws_size, hipStream_t stream) {
  const float* query = (const float*)d_in[0];
  const float* key = (const float*)d_in[1];
  const float* value = (const float*)d_in[2];
  const float* w_q = (const float*)d_in[3];
  const float* b_q = (const float*)d_in[4];
  const float* w_k = (const float*)d_in[5];
  const float* b_k = (const float*)d_in[6];
  const float* w_v = (const float*)d_in[7];
  const float* b_v = (const float*)d_in[8];
  const float* w_o = (const float*)d_in[9];
  const float* b_o = (const float*)d_in[10];

  u16* Qw = (u16*)d_ws;                 // [B,H,S,64] bf16, 8MB
  u16* Kw = Qw + (1 << 22);             // 8MB
  u16* Vw = Kw + (1 << 22);             // 8MB
  u16* Aw = Vw + (1 << 22);             // attn out [B,S,1024] bf16, 8MB

  dim3 blk(256);
  qkv_gemm<<<dim3(8, 32, 3), blk, 0, stream>>>(query, key, value, w_q, w_k,
                                               w_v, b_q, b_k, b_v, Qw, Kw, Vw);
  attn_kernel<<<dim3(32, 16, 2), blk, 0, stream>>>(Qw, Kw, Vw, Aw);
  out_gemm<<<dim3(8, 32), blk, 0, stream>>>(Aw, w_o, b_o, (float*)d_out);
}

// Round 2
// 113.627 us; speedup vs baseline: 1.2104x; 1.2104x over previous
//
#include <hip/hip_runtime.h>

typedef unsigned short u16;
typedef u16 u16x8 __attribute__((ext_vector_type(8)));
typedef __bf16 bf16x8 __attribute__((ext_vector_type(8)));
typedef float f32x4 __attribute__((ext_vector_type(4)));

#define MFMA16 __builtin_amdgcn_mfma_f32_16x16x32_bf16

// fp32 -> bf16 round-to-nearest-even
__device__ __forceinline__ u16 f2bf(float f) {
  unsigned u = __builtin_bit_cast(unsigned, f);
  u += 0x7FFFu + ((u >> 16) & 1u);
  return (u16)(u >> 16);
}

// XOR-swizzled LDS byte address for 64-bf16 (128B) rows (guide G4).
__device__ __forceinline__ int swz(int row, int bcol) {
  return row * 128 + (bcol ^ ((row & 7) << 4));
}

// global -> LDS direct DMA, 16B per lane. lds ptr must be wave-uniform base;
// HW adds lane*16.
__device__ __forceinline__ void gl16(const u16* g, u16* l) {
  __builtin_amdgcn_global_load_lds(
      (const __attribute__((address_space(1))) unsigned int*)g,
      (__attribute__((address_space(3))) unsigned int*)l, 16, 0, 0);
}

// ---------------------------------------------------------------------------
// fp32 -> bf16 cast pass. grid (2048, 7): y selects array.
// ---------------------------------------------------------------------------
__global__ __launch_bounds__(256)
void cast7(const float* __restrict__ a0, const float* __restrict__ a1,
           const float* __restrict__ a2, const float* __restrict__ a3,
           const float* __restrict__ a4, const float* __restrict__ a5,
           const float* __restrict__ a6, u16* __restrict__ ws) {
  const int y = blockIdx.y;
  const float* s;
  u16* d;
  int n;
  // ws layout (u16 elements): Wq 0, Wk 1M, Wv 2M, Wo 3M, Xq 4M, Xk 8M, Xv 12M
  switch (y) {
    case 0: s = a0; d = ws + 4194304; n = 4194304; break;  // query -> Xq
    case 1: s = a1; d = ws + 8388608; n = 4194304; break;  // key   -> Xk
    case 2: s = a2; d = ws + 12582912; n = 4194304; break; // value -> Xv
    case 3: s = a3; d = ws + 0; n = 1048576; break;        // w_q
    case 4: s = a4; d = ws + 1048576; n = 1048576; break;  // w_k
    case 5: s = a5; d = ws + 2097152; n = 1048576; break;  // w_v
    default: s = a6; d = ws + 3145728; n = 1048576; break; // w_o
  }
  const int i = (blockIdx.x * 256 + threadIdx.x) * 8;
  if (i >= n) return;
  float4 v0 = *(const float4*)(s + i);
  float4 v1 = *(const float4*)(s + i + 4);
  u16x8 p = {f2bf(v0.x), f2bf(v0.y), f2bf(v0.z), f2bf(v0.w),
             f2bf(v1.x), f2bf(v1.y), f2bf(v1.z), f2bf(v1.w)};
  *(u16x8*)(d + i) = p;
}

// ---------------------------------------------------------------------------
// bf16 GEMM core: C_tile = A[128,K] @ B[128,K]^T via global_load_lds staging.
// 128x128 tile, BK=64, 4 waves (2x2). A,B row-major bf16 with ld=1024, K=1024.
// ---------------------------------------------------------------------------
struct GemmAcc {
  f32x4 acc[4][4];
};

__device__ __forceinline__ void gemm_core(const u16* __restrict__ A,
                                          const u16* __restrict__ B, int m0,
                                          int n0, u16* As, u16* Bs,
                                          GemmAcc& R) {
  const int tid = threadIdx.x, lane = tid & 63, w = tid >> 6;
  const int wr = w >> 1, wc = w & 1;
  const int r = lane & 15, g = lane >> 4;
  // per-lane source mapping for linear-dest/inverse-swizzled-source staging:
  // lane covers LDS bytes base + lane*16; row = w*32 + i*8 + (lane>>3),
  // source element col = ((lane&7) ^ (lane>>3)) * 8 (XOR involution).
  const int crow = lane >> 3;
  const int ce = ((lane & 7) ^ crow) * 8;
  const u16* Ag = A + (m0 + w * 32 + crow) * 1024 + ce;
  const u16* Bg = B + (n0 + w * 32 + crow) * 1024 + ce;
  u16* Al = As + w * 2048;  // wave-uniform LDS base (bytes w*4096)
  u16* Bl = Bs + w * 2048;

  for (int kt = 0; kt < 16; ++kt) {
    __syncthreads();
#pragma unroll
    for (int i = 0; i < 4; ++i) {
      gl16(Ag + kt * 64 + i * 8192, Al + i * 512);
      gl16(Bg + kt * 64 + i * 8192, Bl + i * 512);
    }
    __syncthreads();
#pragma unroll
    for (int kk = 0; kk < 2; ++kk) {
      bf16x8 af[4], bfr[4];
#pragma unroll
      for (int m = 0; m < 4; ++m)
        af[m] = __builtin_bit_cast(
            bf16x8, *(const u16x8*)((char*)As +
                                    swz(wr * 64 + m * 16 + r, kk * 64 + g * 16)));
#pragma unroll
      for (int n = 0; n < 4; ++n)
        bfr[n] = __builtin_bit_cast(
            bf16x8, *(const u16x8*)((char*)Bs +
                                    swz(wc * 64 + n * 16 + r, kk * 64 + g * 16)));
#pragma unroll
      for (int m = 0; m < 4; ++m)
#pragma unroll
        for (int n = 0; n < 4; ++n)
          R.acc[m][n] = MFMA16(af[m], bfr[n], R.acc[m][n], 0, 0, 0);
    }
  }
}

// ---------------------------------------------------------------------------
// QKV projection from pre-cast bf16: writes bf16 [B,H,S,64].
// grid (8, 32, 3).
// ---------------------------------------------------------------------------
__global__ __launch_bounds__(256)
void qkv_gemm(const u16* __restrict__ ws_in, const float* __restrict__ c0,
              const float* __restrict__ c1, const float* __restrict__ c2,
              u16* __restrict__ o0, u16* __restrict__ o1,
              u16* __restrict__ o2) {
  const int z = blockIdx.z;
  const u16* X = ws_in + 4194304 + z * 4194304;
  const u16* W = ws_in + z * 1048576;
  const float* Bi = (z == 0) ? c0 : (z == 1) ? c1 : c2;
  u16* O = (z == 0) ? o0 : (z == 1) ? o1 : o2;

  const int m0 = blockIdx.y * 128, n0 = blockIdx.x * 128;
  const int tid = threadIdx.x, lane = tid & 63, w = tid >> 6;
  const int wr = w >> 1, wc = w & 1;
  const int r = lane & 15, g = lane >> 4;

  __shared__ u16 As[128 * 64];
  __shared__ u16 Bs[128 * 64];

  GemmAcc R = {};
  gemm_core(X, W, m0, n0, As, Bs, R);

  // epilogue: C[gm][gn] -> bf16 [B,H,S,64]; C/D layout col=lane&15, row=g*4+q
#pragma unroll
  for (int m = 0; m < 4; ++m) {
#pragma unroll
    for (int n = 0; n < 4; ++n) {
      int gn = n0 + wc * 64 + n * 16 + r;
      int hh = gn >> 6, d = gn & 63;
      float bv = Bi[gn];
#pragma unroll
      for (int q = 0; q < 4; ++q) {
        int gm = m0 + wr * 64 + m * 16 + g * 4 + q;
        int bb = gm >> 11, s = gm & 2047;
        O[((bb * 16 + hh) * 2048 + s) * 64 + d] = f2bf(R.acc[m][n][q] + bv);
      }
    }
  }
}

// ---------------------------------------------------------------------------
// Output projection: C = A(bf16) @ Wo^T + b, fp32 out. grid (8, 32).
// ---------------------------------------------------------------------------
__global__ __launch_bounds__(256)
void out_gemm(const u16* __restrict__ A, const u16* __restrict__ W,
              const float* __restrict__ Bi, float* __restrict__ C) {
  const int m0 = blockIdx.y * 128, n0 = blockIdx.x * 128;
  const int tid = threadIdx.x, lane = tid & 63, w = tid >> 6;
  const int wr = w >> 1, wc = w & 1;
  const int r = lane & 15, g = lane >> 4;

  __shared__ u16 As[128 * 64];
  __shared__ u16 Bs[128 * 64];

  GemmAcc R = {};
  gemm_core(A, W, m0, n0, As, Bs, R);

#pragma unroll
  for (int m = 0; m < 4; ++m) {
#pragma unroll
    for (int n = 0; n < 4; ++n) {
      int gn = n0 + wc * 64 + n * 16 + r;
      float bv = Bi[gn];
#pragma unroll
      for (int q = 0; q < 4; ++q) {
        int gm = m0 + wr * 64 + m * 16 + g * 4 + q;
        C[gm * 1024 + gn] = R.acc[m][n][q] + bv;
      }
    }
  }
}

// ---------------------------------------------------------------------------
// Sparse flash attention. grid (32 qtiles, 16 heads, 2 batch), 256 threads.
// Tiles per q-tile k: {0} ∪ {k-2, k-1, k}. Mask: j<=i && (i-j<=128 || j<16).
// ---------------------------------------------------------------------------
__global__ __launch_bounds__(256)
void attn_kernel(const u16* __restrict__ Q, const u16* __restrict__ K,
                 const u16* __restrict__ V, u16* __restrict__ O) {
  const int qt = blockIdx.x, h = blockIdx.y, b = blockIdx.z;
  const int tid = threadIdx.x, lane = tid & 63, w = tid >> 6;
  const int r = lane & 15, g = lane >> 4;
  const int q0 = qt * 64;
  const int base = (b * 16 + h) * 131072;  // 2048*64
  const u16* Qb = Q + base;
  const u16* Kb = K + base;
  const u16* Vb = V + base;

  __shared__ u16 Ks[64 * 64];
  __shared__ u16 Vt[64 * 64];   // transposed: Vt[d][j]
  __shared__ u16 Pl[4608];      // 4 waves x 16 rows x 144B stride

  bf16x8 qf[2];
  {
    const u16* qp = Qb + (q0 + w * 16 + r) * 64 + g * 8;
    qf[0] = __builtin_bit_cast(bf16x8, *(const u16x8*)qp);
    qf[1] = __builtin_bit_cast(bf16x8, *(const u16x8*)(qp + 32));
  }

  f32x4 acc[4] = {};
  float m_run[4] = {-1e30f, -1e30f, -1e30f, -1e30f};
  float l_run[4] = {};

  const int nt = (qt <= 3) ? (qt + 1) : 4;
  const int srow = tid >> 3, sc = (tid & 7) * 8;

  for (int tix = 0; tix < nt; ++tix) {
    const int t = (tix == 0) ? 0 : ((qt <= 3) ? tix : (qt - 3 + tix));
    const int j0 = t * 64;
    __syncthreads();
#pragma unroll
    for (int i = 0; i < 2; ++i) {
      int row = i * 32 + srow;
      u16x8 kv = *(const u16x8*)(Kb + (j0 + row) * 64 + sc);
      *(u16x8*)((char*)Ks + swz(row, sc * 2)) = kv;
      u16x8 vv = *(const u16x8*)(Vb + (j0 + row) * 64 + sc);
#pragma unroll
      for (int qq = 0; qq < 8; ++qq) {
        int d = sc + qq;
        *(u16*)((char*)Vt + d * 128 + ((2 * row) ^ ((d & 7) << 4))) = vv[qq];
      }
    }
    __syncthreads();

    // S = Q K^T
    f32x4 S[4] = {};
#pragma unroll
    for (int kk = 0; kk < 2; ++kk)
#pragma unroll
      for (int n = 0; n < 4; ++n) {
        bf16x8 kf = __builtin_bit_cast(
            bf16x8,
            *(const u16x8*)((char*)Ks + swz(n * 16 + r, kk * 64 + g * 16)));
        S[n] = MFMA16(qf[kk], kf, S[n], 0, 0, 0);
      }

    float mloc[4] = {-1e30f, -1e30f, -1e30f, -1e30f};
#pragma unroll
    for (int n = 0; n < 4; ++n) {
      int j = j0 + n * 16 + r;
#pragma unroll
      for (int q = 0; q < 4; ++q) {
        int i = q0 + w * 16 + g * 4 + q;
        bool ok = (j <= i) && (((i - j) <= 128) || (j < 16));
        float s = ok ? S[n][q] * 0.125f : -1e30f;
        S[n][q] = s;
        mloc[q] = fmaxf(mloc[q], s);
      }
    }
#pragma unroll
    for (int q = 0; q < 4; ++q)
#pragma unroll
      for (int off = 1; off < 16; off <<= 1)
        mloc[q] = fmaxf(mloc[q], __shfl_xor(mloc[q], off));

    float alpha[4], rsum[4] = {};
#pragma unroll
    for (int q = 0; q < 4; ++q) {
      float mn = fmaxf(m_run[q], mloc[q]);
      alpha[q] = __expf(m_run[q] - mn);
      m_run[q] = mn;
    }
#pragma unroll
    for (int n = 0; n < 4; ++n)
#pragma unroll
      for (int q = 0; q < 4; ++q) {
        float p = __expf(S[n][q] - m_run[q]);
        S[n][q] = p;
        rsum[q] += p;
      }
#pragma unroll
    for (int q = 0; q < 4; ++q) {
#pragma unroll
      for (int off = 1; off < 16; off <<= 1)
        rsum[q] += __shfl_xor(rsum[q], off);
      l_run[q] = l_run[q] * alpha[q] + rsum[q];
    }
#pragma unroll
    for (int n = 0; n < 4; ++n) {
      acc[n][0] *= alpha[0];
      acc[n][1] *= alpha[1];
      acc[n][2] *= alpha[2];
      acc[n][3] *= alpha[3];
    }

#pragma unroll
    for (int n = 0; n < 4; ++n)
#pragma unroll
      for (int q = 0; q < 4; ++q)
        *((u16*)((char*)Pl + w * 2304 + (g * 4 + q) * 144) + (n * 16 + r)) =
            f2bf(S[n][q]);

#pragma unroll
    for (int kk = 0; kk < 2; ++kk) {
      bf16x8 pf = __builtin_bit_cast(
          bf16x8,
          *(const u16x8*)((char*)Pl + w * 2304 + r * 144 + kk * 64 + g * 16));
#pragma unroll
      for (int n = 0; n < 4; ++n) {
        bf16x8 vf = __builtin_bit_cast(
            bf16x8,
            *(const u16x8*)((char*)Vt + swz(n * 16 + r, kk * 64 + g * 16)));
        acc[n] = MFMA16(pf, vf, acc[n], 0, 0, 0);
      }
    }
  }

#pragma unroll
  for (int n = 0; n < 4; ++n)
#pragma unroll
    for (int q = 0; q < 4; ++q) {
      int s = q0 + w * 16 + g * 4 + q;
      int d = n * 16 + r;
      O[(b * 2048 + s) * 1024 + h * 64 + d] = f2bf(acc[n][q] / l_run[q]);
    }
}

// ---------------------------------------------------------------------------
extern "C" void kernel_launch(void* const* d_in, const int* in_sizes, int n_in,
                              void* d_out, int out_size, void* d_ws,
                              size_t ws_size, hipStream_t stream) {
  const float* query = (const float*)d_in[0];
  const float* key = (const float*)d_in[1];
  const float* value = (const float*)d_in[2];
  const float* b_q = (const float*)d_in[4];
  const float* b_k = (const float*)d_in[6];
  const float* b_v = (const float*)d_in[8];
  const float* w_o = (const float*)d_in[9];  // unused直接 (cast path)
  const float* b_o = (const float*)d_in[10];
  (void)w_o;

  u16* ws = (u16*)d_ws;
  // ws layout (u16 el): Wq 0 | Wk 1M | Wv 2M | Wo 3M | Xq 4M | Xk 8M | Xv 12M
  //                     Qw 16M | Kw 20M | Vw 24M | Aw aliases Xq (4M)
  u16* Qw = ws + 16777216;
  u16* Kw = ws + 20971520;
  u16* Vw = ws + 25165824;
  u16* Aw = ws + 4194304;  // aliases Xq (dead after qkv_gemm)

  dim3 blk(256);
  cast7<<<dim3(2048, 7), blk, 0, stream>>>(
      (const float*)d_in[0], (const float*)d_in[1], (const float*)d_in[2],
      (const float*)d_in[3], (const float*)d_in[5], (const float*)d_in[7],
      (const float*)d_in[9], ws);
  (void)query; (void)key; (void)value;
  qkv_gemm<<<dim3(8, 32, 3), blk, 0, stream>>>(ws, b_q, b_k, b_v, Qw, Kw, Vw);
  attn_kernel<<<dim3(32, 16, 2), blk, 0, stream>>>(Qw, Kw, Vw, Aw);
  out_gemm<<<dim3(8, 32), blk, 0, stream>>>(Aw, ws + 3145728, b_o,
                                            (float*)d_out);
}

// Round 3
// 105.065 us; speedup vs baseline: 1.3090x; 1.0815x over previous
//
#include <hip/hip_runtime.h>

typedef unsigned short u16;
typedef u16 u16x8 __attribute__((ext_vector_type(8)));
typedef __bf16 bf16x8 __attribute__((ext_vector_type(8)));
typedef float f32x4 __attribute__((ext_vector_type(4)));

#define MFMA16 __builtin_amdgcn_mfma_f32_16x16x32_bf16

// fp32 -> bf16 round-to-nearest-even
__device__ __forceinline__ u16 f2bf(float f) {
  unsigned u = __builtin_bit_cast(unsigned, f);
  u += 0x7FFFu + ((u >> 16) & 1u);
  return (u16)(u >> 16);
}

// XOR-swizzled LDS byte address for 64-bf16 (128B) rows (guide G4).
__device__ __forceinline__ int swz(int row, int bcol) {
  return row * 128 + (bcol ^ ((row & 7) << 4));
}

// global -> LDS direct DMA, 16B per lane. lds ptr must be wave-uniform base;
// HW adds lane*16.
__device__ __forceinline__ void gl16(const u16* g, u16* l) {
  __builtin_amdgcn_global_load_lds(
      (const __attribute__((address_space(1))) unsigned int*)g,
      (__attribute__((address_space(3))) unsigned int*)l, 16, 0, 0);
}

// raw workgroup barrier WITHOUT the vmcnt(0) drain __syncthreads would add;
// asm memory clobbers pin compiler-level memory-op ordering across it.
__device__ __forceinline__ void BARR() {
  asm volatile("" ::: "memory");
  __builtin_amdgcn_s_barrier();
  asm volatile("" ::: "memory");
}

// ---------------------------------------------------------------------------
// fp32 -> bf16 cast pass. grid (2048, 7): y selects array.
// ---------------------------------------------------------------------------
__global__ __launch_bounds__(256)
void cast7(const float* __restrict__ a0, const float* __restrict__ a1,
           const float* __restrict__ a2, const float* __restrict__ a3,
           const float* __restrict__ a4, const float* __restrict__ a5,
           const float* __restrict__ a6, u16* __restrict__ ws) {
  const int y = blockIdx.y;
  const float* s;
  u16* d;
  int n;
  // ws layout (u16 elements): Wq 0, Wk 1M, Wv 2M, Wo 3M, Xq 4M, Xk 8M, Xv 12M
  switch (y) {
    case 0: s = a0; d = ws + 4194304; n = 4194304; break;  // query -> Xq
    case 1: s = a1; d = ws + 8388608; n = 4194304; break;  // key   -> Xk
    case 2: s = a2; d = ws + 12582912; n = 4194304; break; // value -> Xv
    case 3: s = a3; d = ws + 0; n = 1048576; break;        // w_q
    case 4: s = a4; d = ws + 1048576; n = 1048576; break;  // w_k
    case 5: s = a5; d = ws + 2097152; n = 1048576; break;  // w_v
    default: s = a6; d = ws + 3145728; n = 1048576; break; // w_o
  }
  const int i = (blockIdx.x * 256 + threadIdx.x) * 8;
  if (i >= n) return;
  float4 v0 = *(const float4*)(s + i);
  float4 v1 = *(const float4*)(s + i + 4);
  u16x8 p = {f2bf(v0.x), f2bf(v0.y), f2bf(v0.z), f2bf(v0.w),
             f2bf(v1.x), f2bf(v1.y), f2bf(v1.z), f2bf(v1.w)};
  *(u16x8*)(d + i) = p;
}

// ---------------------------------------------------------------------------
// QKV projection, 256x256 tile, 4-phase counted-vmcnt pipeline.
// 512 threads = 8 waves (wm = w>>2, wn = w&3); per-wave C = 128x64.
// LDS 128KB: 2 bufs x (A 32KB + B 32KB), chunk = 64 rows (8KB).
// Schedule per K-tile t (buf = t&1):
//   ph1: stage B0,B1,B2[t+1]->buf^1 | read A-lo + B n0-1 | 16 MFMA | bar
//   ph2: stage B3,A1,A2[t+1]->buf^1 | read B n2-3        | 16 MFMA | bar
//   ph3: stage A0[t+2]->buf          | read A-hi          | 16 MFMA | bar
//   ph4: stage A3[t+2]->buf          |                    | 16 MFMA |
//        vmcnt(2) (retires all tile-t+1 loads; A0,A3[t+2] stay in flight) | bar
// Region-safety: A0/A2 last read ph1, A1/A3 ph3, B ph2 -> every stage target
// was freed by an earlier barrier. Raw s_barrier (no vmcnt drain).
// ---------------------------------------------------------------------------
#define STGA(tt, c)                                                         \
  gl16(A + (m0 + (c)*64 + (w << 3) + (lane >> 3)) * 1024 + (tt)*64 +        \
           (((lane & 7) ^ (lane >> 3)) << 3),                               \
       (u16*)(sb + (((tt)&1) << 16) + (c)*8192 + (w << 10)))
#define STGB(tt, c)                                                         \
  gl16(B + (n0 + (c)*64 + (w << 3) + (lane >> 3)) * 1024 + (tt)*64 +        \
           (((lane & 7) ^ (lane >> 3)) << 3),                               \
       (u16*)(sb + (((tt)&1) << 16) + 32768 + (c)*8192 + (w << 10)))

__global__ __launch_bounds__(512)
void qkv_gemm256(const u16* __restrict__ ws_in, const float* __restrict__ c0,
                 const float* __restrict__ c1, const float* __restrict__ c2,
                 u16* __restrict__ o0, u16* __restrict__ o1,
                 u16* __restrict__ o2) {
  // bijective XCD chunk swizzle over 192 blocks (192 % 8 == 0)
  const int bid = blockIdx.x;
  const int s = (bid & 7) * 24 + (bid >> 3);
  const int z = s >> 6;
  const int rem = s & 63;
  const int m0 = (rem >> 2) << 8;
  const int n0 = (rem & 3) << 8;

  const u16* __restrict__ A = ws_in + 4194304 + z * 4194304;
  const u16* __restrict__ B = ws_in + z * 1048576;
  const float* Bi = (z == 0) ? c0 : (z == 1) ? c1 : c2;
  u16* O = (z == 0) ? o0 : (z == 1) ? o1 : o2;

  const int tid = threadIdx.x, lane = tid & 63, w = tid >> 6;
  const int wm = w >> 2, wn = w & 3;
  const int r = lane & 15, g = lane >> 4;

  __shared__ u16 SH[65536];  // 128 KB
  char* sb = (char*)SH;

  f32x4 acc[8][4] = {};
  bf16x8 af[2][4], bf[2][4];

  const int colr0 = (g * 16) ^ ((r & 7) << 4);        // kk=0 byte col
  const int colr1 = (64 + g * 16) ^ ((r & 7) << 4);   // kk=1 byte col
  const int rowAb = (wm * 128 + r) * 128;             // A row base (bytes)
  const int rowBb = 32768 + (wn * 64 + r) * 128;      // B row base (bytes)

#define LDA(half)                                                           \
  _Pragma("unroll") for (int m = 0; m < 4; ++m) {                           \
    char* p = sb + bo + rowAb + ((half)*64 + m * 16) * 128;                 \
    af[0][m] = __builtin_bit_cast(bf16x8, *(const u16x8*)(p + colr0));      \
    af[1][m] = __builtin_bit_cast(bf16x8, *(const u16x8*)(p + colr1));      \
  }
#define LDB(n)                                                              \
  {                                                                         \
    char* p = sb + bo + rowBb + (n)*16 * 128;                               \
    bf[0][n] = __builtin_bit_cast(bf16x8, *(const u16x8*)(p + colr0));      \
    bf[1][n] = __builtin_bit_cast(bf16x8, *(const u16x8*)(p + colr1));      \
  }
#define FMA(mh, nl)                                                         \
  __builtin_amdgcn_s_setprio(1);                                           \
  _Pragma("unroll") for (int m = 0; m < 4; ++m)                             \
  _Pragma("unroll") for (int n = 0; n < 2; ++n) {                           \
    acc[(mh)*4 + m][(nl)*2 + n] =                                           \
        MFMA16(af[0][m], bf[0][(nl)*2 + n], acc[(mh)*4 + m][(nl)*2 + n], 0, \
               0, 0);                                                       \
    acc[(mh)*4 + m][(nl)*2 + n] =                                           \
        MFMA16(af[1][m], bf[1][(nl)*2 + n], acc[(mh)*4 + m][(nl)*2 + n], 0, \
               0, 0);                                                       \
  }                                                                         \
  __builtin_amdgcn_s_setprio(0);

  // prologue: tiles 0 and 1 fully issued; wait for tile 0 (8 newest pending)
#pragma unroll
  for (int c = 0; c < 4; ++c) STGB(0, c);
#pragma unroll
  for (int c = 0; c < 4; ++c) STGA(0, c);
#pragma unroll
  for (int c = 0; c < 4; ++c) STGB(1, c);
#pragma unroll
  for (int c = 0; c < 4; ++c) STGA(1, c);
  asm volatile("s_waitcnt vmcnt(8)" ::: "memory");
  __builtin_amdgcn_s_barrier();
  asm volatile("" ::: "memory");

  for (int t = 0; t < 16; ++t) {
    const int bo = (t & 1) << 16;
    // ---- phase 1
    if (t >= 1 && t < 15) { STGB(t + 1, 0); STGB(t + 1, 1); STGB(t + 1, 2); }
    LDA(0);
    LDB(0);
    LDB(1);
    FMA(0, 0);
    BARR();
    // ---- phase 2
    if (t >= 1 && t < 15) { STGB(t + 1, 3); STGA(t + 1, 1); STGA(t + 1, 2); }
    LDB(2);
    LDB(3);
    FMA(0, 1);
    BARR();
    // ---- phase 3
    if (t < 14) STGA(t + 2, 0);
    LDA(1);
    FMA(1, 0);
    BARR();
    // ---- phase 4
    if (t < 14) STGA(t + 2, 3);
    FMA(1, 1);
    if (t < 14)
      asm volatile("s_waitcnt vmcnt(2)" ::: "memory");
    else
      asm volatile("s_waitcnt vmcnt(0)" ::: "memory");
    BARR();
  }

  // epilogue: C/D layout col=lane&15, row=g*4+q -> bf16 [B,H,S,64]
#pragma unroll
  for (int n = 0; n < 4; ++n) {
    const int gn = n0 + wn * 64 + n * 16 + r;
    const int hh = gn >> 6, d = gn & 63;
    const float bv = Bi[gn];
#pragma unroll
    for (int m = 0; m < 8; ++m) {
#pragma unroll
      for (int q = 0; q < 4; ++q) {
        int gm = m0 + wm * 128 + m * 16 + g * 4 + q;
        int bb = gm >> 11, sIdx = gm & 2047;
        O[((bb * 16 + hh) * 2048 + sIdx) * 64 + d] = f2bf(acc[m][n][q] + bv);
      }
    }
  }
#undef LDA
#undef LDB
#undef FMA
}

// ---------------------------------------------------------------------------
// 128x128 bf16 GEMM core (m97-style) — kept for out_gemm.
// ---------------------------------------------------------------------------
struct GemmAcc {
  f32x4 acc[4][4];
};

__device__ __forceinline__ void gemm_core(const u16* __restrict__ A,
                                          const u16* __restrict__ B, int m0,
                                          int n0, u16* As, u16* Bs,
                                          GemmAcc& R) {
  const int tid = threadIdx.x, lane = tid & 63, w = tid >> 6;
  const int wr = w >> 1, wc = w & 1;
  const int r = lane & 15, g = lane >> 4;
  const int crow = lane >> 3;
  const int ce = ((lane & 7) ^ crow) * 8;
  const u16* Ag = A + (m0 + w * 32 + crow) * 1024 + ce;
  const u16* Bg = B + (n0 + w * 32 + crow) * 1024 + ce;
  u16* Al = As + w * 2048;
  u16* Bl = Bs + w * 2048;

  for (int kt = 0; kt < 16; ++kt) {
    __syncthreads();
#pragma unroll
    for (int i = 0; i < 4; ++i) {
      gl16(Ag + kt * 64 + i * 8192, Al + i * 512);
      gl16(Bg + kt * 64 + i * 8192, Bl + i * 512);
    }
    __syncthreads();
#pragma unroll
    for (int kk = 0; kk < 2; ++kk) {
      bf16x8 af[4], bfr[4];
#pragma unroll
      for (int m = 0; m < 4; ++m)
        af[m] = __builtin_bit_cast(
            bf16x8, *(const u16x8*)((char*)As +
                                    swz(wr * 64 + m * 16 + r, kk * 64 + g * 16)));
#pragma unroll
      for (int n = 0; n < 4; ++n)
        bfr[n] = __builtin_bit_cast(
            bf16x8, *(const u16x8*)((char*)Bs +
                                    swz(wc * 64 + n * 16 + r, kk * 64 + g * 16)));
#pragma unroll
      for (int m = 0; m < 4; ++m)
#pragma unroll
        for (int n = 0; n < 4; ++n)
          R.acc[m][n] = MFMA16(af[m], bfr[n], R.acc[m][n], 0, 0, 0);
    }
  }
}

// ---------------------------------------------------------------------------
// Output projection: C = A(bf16) @ Wo^T + b, fp32 out. grid (8, 32).
// ---------------------------------------------------------------------------
__global__ __launch_bounds__(256)
void out_gemm(const u16* __restrict__ A, const u16* __restrict__ W,
              const float* __restrict__ Bi, float* __restrict__ C) {
  const int m0 = blockIdx.y * 128, n0 = blockIdx.x * 128;
  const int tid = threadIdx.x, lane = tid & 63, w = tid >> 6;
  const int wr = w >> 1, wc = w & 1;
  const int r = lane & 15, g = lane >> 4;

  __shared__ u16 As[128 * 64];
  __shared__ u16 Bs[128 * 64];

  GemmAcc R = {};
  gemm_core(A, W, m0, n0, As, Bs, R);

#pragma unroll
  for (int m = 0; m < 4; ++m) {
#pragma unroll
    for (int n = 0; n < 4; ++n) {
      int gn = n0 + wc * 64 + n * 16 + r;
      float bv = Bi[gn];
#pragma unroll
      for (int q = 0; q < 4; ++q) {
        int gm = m0 + wr * 64 + m * 16 + g * 4 + q;
        C[gm * 1024 + gn] = R.acc[m][n][q] + bv;
      }
    }
  }
}

// ---------------------------------------------------------------------------
// Sparse flash attention. grid (32 qtiles, 16 heads, 2 batch), 256 threads.
// Tiles per q-tile k: {0} ∪ {k-2, k-1, k}. Mask: j<=i && (i-j<=128 || j<16).
// ---------------------------------------------------------------------------
__global__ __launch_bounds__(256)
void attn_kernel(const u16* __restrict__ Q, const u16* __restrict__ K,
                 const u16* __restrict__ V, u16* __restrict__ O) {
  const int qt = blockIdx.x, h = blockIdx.y, b = blockIdx.z;
  const int tid = threadIdx.x, lane = tid & 63, w = tid >> 6;
  const int r = lane & 15, g = lane >> 4;
  const int q0 = qt * 64;
  const int base = (b * 16 + h) * 131072;  // 2048*64
  const u16* Qb = Q + base;
  const u16* Kb = K + base;
  const u16* Vb = V + base;

  __shared__ u16 Ks[64 * 64];
  __shared__ u16 Vt[64 * 64];   // transposed: Vt[d][j]
  __shared__ u16 Pl[4608];      // 4 waves x 16 rows x 144B stride

  bf16x8 qf[2];
  {
    const u16* qp = Qb + (q0 + w * 16 + r) * 64 + g * 8;
    qf[0] = __builtin_bit_cast(bf16x8, *(const u16x8*)qp);
    qf[1] = __builtin_bit_cast(bf16x8, *(const u16x8*)(qp + 32));
  }

  f32x4 acc[4] = {};
  float m_run[4] = {-1e30f, -1e30f, -1e30f, -1e30f};
  float l_run[4] = {};

  const int nt = (qt <= 3) ? (qt + 1) : 4;
  const int srow = tid >> 3, sc = (tid & 7) * 8;

  for (int tix = 0; tix < nt; ++tix) {
    const int t = (tix == 0) ? 0 : ((qt <= 3) ? tix : (qt - 3 + tix));
    const int j0 = t * 64;
    __syncthreads();
#pragma unroll
    for (int i = 0; i < 2; ++i) {
      int row = i * 32 + srow;
      u16x8 kv = *(const u16x8*)(Kb + (j0 + row) * 64 + sc);
      *(u16x8*)((char*)Ks + swz(row, sc * 2)) = kv;
      u16x8 vv = *(const u16x8*)(Vb + (j0 + row) * 64 + sc);
#pragma unroll
      for (int qq = 0; qq < 8; ++qq) {
        int d = sc + qq;
        *(u16*)((char*)Vt + d * 128 + ((2 * row) ^ ((d & 7) << 4))) = vv[qq];
      }
    }
    __syncthreads();

    // S = Q K^T
    f32x4 S[4] = {};
#pragma unroll
    for (int kk = 0; kk < 2; ++kk)
#pragma unroll
      for (int n = 0; n < 4; ++n) {
        bf16x8 kf = __builtin_bit_cast(
            bf16x8,
            *(const u16x8*)((char*)Ks + swz(n * 16 + r, kk * 64 + g * 16)));
        S[n] = MFMA16(qf[kk], kf, S[n], 0, 0, 0);
      }

    float mloc[4] = {-1e30f, -1e30f, -1e30f, -1e30f};
#pragma unroll
    for (int n = 0; n < 4; ++n) {
      int j = j0 + n * 16 + r;
#pragma unroll
      for (int q = 0; q < 4; ++q) {
        int i = q0 + w * 16 + g * 4 + q;
        bool ok = (j <= i) && (((i - j) <= 128) || (j < 16));
        float s = ok ? S[n][q] * 0.125f : -1e30f;
        S[n][q] = s;
        mloc[q] = fmaxf(mloc[q], s);
      }
    }
#pragma unroll
    for (int q = 0; q < 4; ++q)
#pragma unroll
      for (int off = 1; off < 16; off <<= 1)
        mloc[q] = fmaxf(mloc[q], __shfl_xor(mloc[q], off));

    float alpha[4], rsum[4] = {};
#pragma unroll
    for (int q = 0; q < 4; ++q) {
      float mn = fmaxf(m_run[q], mloc[q]);
      alpha[q] = __expf(m_run[q] - mn);
      m_run[q] = mn;
    }
#pragma unroll
    for (int n = 0; n < 4; ++n)
#pragma unroll
      for (int q = 0; q < 4; ++q) {
        float p = __expf(S[n][q] - m_run[q]);
        S[n][q] = p;
        rsum[q] += p;
      }
#pragma unroll
    for (int q = 0; q < 4; ++q) {
#pragma unroll
      for (int off = 1; off < 16; off <<= 1)
        rsum[q] += __shfl_xor(rsum[q], off);
      l_run[q] = l_run[q] * alpha[q] + rsum[q];
    }
#pragma unroll
    for (int n = 0; n < 4; ++n) {
      acc[n][0] *= alpha[0];
      acc[n][1] *= alpha[1];
      acc[n][2] *= alpha[2];
      acc[n][3] *= alpha[3];
    }

#pragma unroll
    for (int n = 0; n < 4; ++n)
#pragma unroll
      for (int q = 0; q < 4; ++q)
        *((u16*)((char*)Pl + w * 2304 + (g * 4 + q) * 144) + (n * 16 + r)) =
            f2bf(S[n][q]);

#pragma unroll
    for (int kk = 0; kk < 2; ++kk) {
      bf16x8 pf = __builtin_bit_cast(
          bf16x8,
          *(const u16x8*)((char*)Pl + w * 2304 + r * 144 + kk * 64 + g * 16));
#pragma unroll
      for (int n = 0; n < 4; ++n) {
        bf16x8 vf = __builtin_bit_cast(
            bf16x8,
            *(const u16x8*)((char*)Vt + swz(n * 16 + r, kk * 64 + g * 16)));
        acc[n] = MFMA16(pf, vf, acc[n], 0, 0, 0);
      }
    }
  }

#pragma unroll
  for (int n = 0; n < 4; ++n)
#pragma unroll
    for (int q = 0; q < 4; ++q) {
      int s = q0 + w * 16 + g * 4 + q;
      int d = n * 16 + r;
      O[(b * 2048 + s) * 1024 + h * 64 + d] = f2bf(acc[n][q] / l_run[q]);
    }
}

// ---------------------------------------------------------------------------
extern "C" void kernel_launch(void* const* d_in, const int* in_sizes, int n_in,
                              void* d_out, int out_size, void* d_ws,
                              size_t ws_size, hipStream_t stream) {
  const float* b_q = (const float*)d_in[4];
  const float* b_k = (const float*)d_in[6];
  const float* b_v = (const float*)d_in[8];
  const float* b_o = (const float*)d_in[10];

  u16* ws = (u16*)d_ws;
  // ws layout (u16 el): Wq 0 | Wk 1M | Wv 2M | Wo 3M | Xq 4M | Xk 8M | Xv 12M
  //                     Qw 16M | Kw 20M | Vw 24M | Aw aliases Xq (4M)
  u16* Qw = ws + 16777216;
  u16* Kw = ws + 20971520;
  u16* Vw = ws + 25165824;
  u16* Aw = ws + 4194304;  // aliases Xq (dead after qkv projection)

  cast7<<<dim3(2048, 7), dim3(256), 0, stream>>>(
      (const float*)d_in[0], (const float*)d_in[1], (const float*)d_in[2],
      (const float*)d_in[3], (const float*)d_in[5], (const float*)d_in[7],
      (const float*)d_in[9], ws);
  qkv_gemm256<<<dim3(192), dim3(512), 0, stream>>>(ws, b_q, b_k, b_v, Qw, Kw,
                                                   Vw);
  attn_kernel<<<dim3(32, 16, 2), dim3(256), 0, stream>>>(Qw, Kw, Vw, Aw);
  out_gemm<<<dim3(8, 32), dim3(256), 0, stream>>>(Aw, ws + 3145728, b_o,
                                                  (float*)d_out);
}

// Round 4
// 96.042 us; speedup vs baseline: 1.4320x; 1.0940x over previous
//
#include <hip/hip_runtime.h>

typedef unsigned short u16;
typedef u16 u16x8 __attribute__((ext_vector_type(8)));
typedef __bf16 bf16x8 __attribute__((ext_vector_type(8)));
typedef float f32x4 __attribute__((ext_vector_type(4)));

#define MFMA16 __builtin_amdgcn_mfma_f32_16x16x32_bf16

__device__ __forceinline__ u16 f2bf(float f) {
  unsigned u = __builtin_bit_cast(unsigned, f);
  u += 0x7FFFu + ((u >> 16) & 1u);
  return (u16)(u >> 16);
}

// XOR-swizzled LDS byte address for 64-bf16 (128B) rows (guide G4).
__device__ __forceinline__ int swz(int row, int bcol) {
  return row * 128 + (bcol ^ ((row & 7) << 4));
}

__device__ __forceinline__ void gl16(const u16* g, u16* l) {
  __builtin_amdgcn_global_load_lds(
      (const __attribute__((address_space(1))) unsigned int*)g,
      (__attribute__((address_space(3))) unsigned int*)l, 16, 0, 0);
}

// raw workgroup barrier (no vmcnt(0) drain); memory clobbers pin LDS/global
// ops (ds_read/global_load_lds) across it, MFMA (reg-only) may float — safe.
__device__ __forceinline__ void BARR() {
  asm volatile("" ::: "memory");
  __builtin_amdgcn_s_barrier();
  asm volatile("" ::: "memory");
}
#define VMCNT(n) asm volatile("s_waitcnt vmcnt(" #n ")" ::: "memory")

// ---------------------------------------------------------------------------
// fp32 -> bf16 cast pass. grid (2048, 7).
// ---------------------------------------------------------------------------
__global__ __launch_bounds__(256)
void cast7(const float* __restrict__ a0, const float* __restrict__ a1,
           const float* __restrict__ a2, const float* __restrict__ a3,
           const float* __restrict__ a4, const float* __restrict__ a5,
           const float* __restrict__ a6, u16* __restrict__ ws) {
  const int y = blockIdx.y;
  const float* s;
  u16* d;
  int n;
  switch (y) {
    case 0: s = a0; d = ws + 4194304; n = 4194304; break;
    case 1: s = a1; d = ws + 8388608; n = 4194304; break;
    case 2: s = a2; d = ws + 12582912; n = 4194304; break;
    case 3: s = a3; d = ws + 0; n = 1048576; break;
    case 4: s = a4; d = ws + 1048576; n = 1048576; break;
    case 5: s = a5; d = ws + 2097152; n = 1048576; break;
    default: s = a6; d = ws + 3145728; n = 1048576; break;
  }
  const int i = (blockIdx.x * 256 + threadIdx.x) * 8;
  if (i >= n) return;
  float4 v0 = *(const float4*)(s + i);
  float4 v1 = *(const float4*)(s + i + 4);
  u16x8 p = {f2bf(v0.x), f2bf(v0.y), f2bf(v0.z), f2bf(v0.w),
             f2bf(v1.x), f2bf(v1.y), f2bf(v1.z), f2bf(v1.w)};
  *(u16x8*)(d + i) = p;
}

// ---------------------------------------------------------------------------
// QKV projection, 256x256 tile, 2-phase counted-vmcnt pipeline.
// 512 threads = 8 waves (wm=w>>2, wn=w&3); per-wave C = 128x64.
// LDS 128KB: 2 bufs x (A 32KB + B 32KB). Chunk = 64 rows, 1 gl16/wave/chunk.
// Per K-tile t (buf=t&1):
//  ph1: STG B0-3[t+1]->buf^1 | dsr A-lo(8)+B(8) | 32 MFMA | vmcnt(4) | bar
//  ph2: STG A0,A2,A1,A3[t+1]->buf^1 | dsr A-hi(8) | 32 MFMA | vmcnt(2) | bar
// Discipline: every dsr retires (FMA lgkm) before the phase barrier; each
// staged region's last reader is >=1 barrier back. vmcnt(2) retires B[t+1]+
// A0,A2[t+1] (needed next ph1); vmcnt(4) retires A1,A3[t+1] (needed next ph2).
// ---------------------------------------------------------------------------
#define STGA(tt, c)                                                         \
  gl16(A + (m0 + (c)*64 + (w << 3) + (lane >> 3)) * 1024 + (tt)*64 +        \
           (((lane & 7) ^ (lane >> 3)) << 3),                               \
       (u16*)(sb + (((tt)&1) << 16) + (c)*8192 + (w << 10)))
#define STGB(tt, c)                                                         \
  gl16(B + (n0 + (c)*64 + (w << 3) + (lane >> 3)) * 1024 + (tt)*64 +        \
           (((lane & 7) ^ (lane >> 3)) << 3),                               \
       (u16*)(sb + (((tt)&1) << 16) + 32768 + (c)*8192 + (w << 10)))

__global__ __launch_bounds__(512)
void qkv_gemm256(const u16* __restrict__ ws_in, const float* __restrict__ c0,
                 const float* __restrict__ c1, const float* __restrict__ c2,
                 u16* __restrict__ o0, u16* __restrict__ o1,
                 u16* __restrict__ o2) {
  const int bid = blockIdx.x;
  const int s = (bid & 7) * 24 + (bid >> 3);  // XCD swizzle, 192 % 8 == 0
  const int z = s >> 6;
  const int rem = s & 63;
  const int m0 = (rem >> 2) << 8;
  const int n0 = (rem & 3) << 8;

  const u16* __restrict__ A = ws_in + 4194304 + z * 4194304;
  const u16* __restrict__ B = ws_in + z * 1048576;
  const float* Bi = (z == 0) ? c0 : (z == 1) ? c1 : c2;
  u16* O = (z == 0) ? o0 : (z == 1) ? o1 : o2;

  const int tid = threadIdx.x, lane = tid & 63, w = tid >> 6;
  const int wm = w >> 2, wn = w & 3;
  const int r = lane & 15, g = lane >> 4;

  __shared__ u16 SH[65536];  // 128 KB
  char* sb = (char*)SH;

  f32x4 acc[8][4] = {};
  bf16x8 af[2][4], bf[2][4];

  const int colr0 = (g * 16) ^ ((r & 7) << 4);
  const int colr1 = (64 + g * 16) ^ ((r & 7) << 4);
  const int rowAb = (wm * 128 + r) * 128;
  const int rowBb = 32768 + (wn * 64 + r) * 128;

#define LDA(half)                                                           \
  _Pragma("unroll") for (int m = 0; m < 4; ++m) {                           \
    char* p = sb + bo + rowAb + ((half)*64 + m * 16) * 128;                 \
    af[0][m] = __builtin_bit_cast(bf16x8, *(const u16x8*)(p + colr0));      \
    af[1][m] = __builtin_bit_cast(bf16x8, *(const u16x8*)(p + colr1));      \
  }
#define LDB(n)                                                              \
  {                                                                         \
    char* p = sb + bo + rowBb + (n)*16 * 128;                               \
    bf[0][n] = __builtin_bit_cast(bf16x8, *(const u16x8*)(p + colr0));      \
    bf[1][n] = __builtin_bit_cast(bf16x8, *(const u16x8*)(p + colr1));      \
  }
#define FMAH(h)                                                             \
  __builtin_amdgcn_s_setprio(1);                                            \
  _Pragma("unroll") for (int m = 0; m < 4; ++m)                             \
  _Pragma("unroll") for (int n = 0; n < 4; ++n) {                           \
    acc[(h)*4 + m][n] = MFMA16(af[0][m], bf[0][n], acc[(h)*4 + m][n], 0, 0, \
                               0);                                          \
    acc[(h)*4 + m][n] = MFMA16(af[1][m], bf[1][n], acc[(h)*4 + m][n], 0, 0, \
                               0);                                          \
  }                                                                         \
  __builtin_amdgcn_s_setprio(0);

  // prologue: tile 0 fully staged
#pragma unroll
  for (int c = 0; c < 4; ++c) STGB(0, c);
#pragma unroll
  for (int c = 0; c < 4; ++c) STGA(0, c);
  VMCNT(0);
  __builtin_amdgcn_s_barrier();
  asm volatile("" ::: "memory");

  for (int t = 0; t < 16; ++t) {
    const int bo = (t & 1) << 16;
    // ---- phase 1: A-lo
    if (t < 15) { STGB(t + 1, 0); STGB(t + 1, 1); STGB(t + 1, 2); STGB(t + 1, 3); }
    LDA(0);
    LDB(0); LDB(1); LDB(2); LDB(3);
    FMAH(0);
    if (t < 15) { VMCNT(4); } else { VMCNT(0); }
    BARR();
    // ---- phase 2: A-hi
    if (t < 15) { STGA(t + 1, 0); STGA(t + 1, 2); STGA(t + 1, 1); STGA(t + 1, 3); }
    LDA(1);
    FMAH(1);
    if (t < 15) { VMCNT(2); }
    BARR();
  }

  // epilogue: C/D layout col=lane&15, row=g*4+q -> bf16 [B,H,S,64]
#pragma unroll
  for (int n = 0; n < 4; ++n) {
    const int gn = n0 + wn * 64 + n * 16 + r;
    const int hh = gn >> 6, d = gn & 63;
    const float bv = Bi[gn];
#pragma unroll
    for (int m = 0; m < 8; ++m) {
#pragma unroll
      for (int q = 0; q < 4; ++q) {
        int gm = m0 + wm * 128 + m * 16 + g * 4 + q;
        int bb = gm >> 11, sIdx = gm & 2047;
        O[((bb * 16 + hh) * 2048 + sIdx) * 64 + d] = f2bf(acc[m][n][q] + bv);
      }
    }
  }
#undef LDA
#undef LDB
#undef FMAH
}

// ---------------------------------------------------------------------------
// Output projection: 128x128 tile, 2-phase pipeline, 4 waves, 64KB LDS
// (2 blocks/CU). A staged 2-ahead, B 1-ahead; one vmcnt(4) per K-tile.
//  ph1: STG B0,B1[t+1]->buf^1 | dsr A(8)+B-lo(4) | 16 MFMA | bar
//  ph2: STG A0,A1[t+2]->buf   | dsr B-hi(4)      | 16 MFMA | vmcnt(4) | bar
// ---------------------------------------------------------------------------
#define OSTGA(tt, c, j)                                                     \
  gl16(Ain + (m0 + (c)*64 + (w << 4) + (j)*8 + (lane >> 3)) * 1024 +        \
           (tt)*64 + (((lane & 7) ^ (lane >> 3)) << 3),                     \
       (u16*)(sb + (((tt)&1) << 15) + (c)*8192 + (w << 11) + ((j) << 10)))
#define OSTGB(tt, c, j)                                                     \
  gl16(W + (n0 + (c)*64 + (w << 4) + (j)*8 + (lane >> 3)) * 1024 +          \
           (tt)*64 + (((lane & 7) ^ (lane >> 3)) << 3),                     \
       (u16*)(sb + (((tt)&1) << 15) + 16384 + (c)*8192 + (w << 11) +        \
              ((j) << 10)))

__global__ __launch_bounds__(256)
void out_gemm_p(const u16* __restrict__ Ain, const u16* __restrict__ W,
                const float* __restrict__ Bi, float* __restrict__ C) {
  const int bid = blockIdx.x;
  const int s = (bid & 7) * 32 + (bid >> 3);  // XCD swizzle, 256 % 8 == 0
  const int m0 = (s >> 3) << 7, n0 = (s & 7) << 7;

  const int tid = threadIdx.x, lane = tid & 63, w = tid >> 6;
  const int wm = w >> 1, wn = w & 1;
  const int r = lane & 15, g = lane >> 4;

  __shared__ u16 SH[32768];  // 64 KB
  char* sb = (char*)SH;

  f32x4 acc[4][4] = {};
  bf16x8 af[2][4], bf[2][4];

  const int colr0 = (g * 16) ^ ((r & 7) << 4);
  const int colr1 = (64 + g * 16) ^ ((r & 7) << 4);
  const int rowAb = (wm * 64 + r) * 128;
  const int rowBb = 16384 + (wn * 64 + r) * 128;

#define OLDA()                                                              \
  _Pragma("unroll") for (int m = 0; m < 4; ++m) {                           \
    char* p = sb + bo + rowAb + m * 16 * 128;                               \
    af[0][m] = __builtin_bit_cast(bf16x8, *(const u16x8*)(p + colr0));      \
    af[1][m] = __builtin_bit_cast(bf16x8, *(const u16x8*)(p + colr1));      \
  }
#define OLDB(n)                                                             \
  {                                                                         \
    char* p = sb + bo + rowBb + (n)*16 * 128;                               \
    bf[0][n] = __builtin_bit_cast(bf16x8, *(const u16x8*)(p + colr0));      \
    bf[1][n] = __builtin_bit_cast(bf16x8, *(const u16x8*)(p + colr1));      \
  }
#define OFMA(nh)                                                            \
  __builtin_amdgcn_s_setprio(1);                                            \
  _Pragma("unroll") for (int m = 0; m < 4; ++m)                             \
  _Pragma("unroll") for (int n = 0; n < 2; ++n) {                           \
    acc[m][(nh)*2 + n] =                                                    \
        MFMA16(af[0][m], bf[0][(nh)*2 + n], acc[m][(nh)*2 + n], 0, 0, 0);   \
    acc[m][(nh)*2 + n] =                                                    \
        MFMA16(af[1][m], bf[1][(nh)*2 + n], acc[m][(nh)*2 + n], 0, 0, 0);   \
  }                                                                         \
  __builtin_amdgcn_s_setprio(0);

  // prologue: A[0], B[0], A[1]; leave A[1] (4 newest) in flight
#pragma unroll
  for (int c = 0; c < 2; ++c) { OSTGA(0, c, 0); OSTGA(0, c, 1); }
#pragma unroll
  for (int c = 0; c < 2; ++c) { OSTGB(0, c, 0); OSTGB(0, c, 1); }
#pragma unroll
  for (int c = 0; c < 2; ++c) { OSTGA(1, c, 0); OSTGA(1, c, 1); }
  VMCNT(4);
  __builtin_amdgcn_s_barrier();
  asm volatile("" ::: "memory");

  for (int t = 0; t < 16; ++t) {
    const int bo = (t & 1) << 15;
    // ---- phase 1
    if (t < 15) { OSTGB(t + 1, 0, 0); OSTGB(t + 1, 0, 1); OSTGB(t + 1, 1, 0); OSTGB(t + 1, 1, 1); }
    OLDA();
    OLDB(0); OLDB(1);
    OFMA(0);
    BARR();
    // ---- phase 2
    if (t < 14) { OSTGA(t + 2, 0, 0); OSTGA(t + 2, 0, 1); OSTGA(t + 2, 1, 0); OSTGA(t + 2, 1, 1); }
    OLDB(2); OLDB(3);
    OFMA(1);
    if (t < 14) { VMCNT(4); } else if (t == 14) { VMCNT(0); }
    BARR();
  }

#pragma unroll
  for (int m = 0; m < 4; ++m) {
#pragma unroll
    for (int n = 0; n < 4; ++n) {
      int gn = n0 + wn * 64 + n * 16 + r;
      float bv = Bi[gn];
#pragma unroll
      for (int q = 0; q < 4; ++q) {
        int gm = m0 + wm * 64 + m * 16 + g * 4 + q;
        C[gm * 1024 + gn] = acc[m][n][q] + bv;
      }
    }
  }
#undef OLDA
#undef OLDB
#undef OFMA
}

// ---------------------------------------------------------------------------
// Sparse flash attention (unchanged). grid (32, 16, 2), 256 threads.
// ---------------------------------------------------------------------------
__global__ __launch_bounds__(256)
void attn_kernel(const u16* __restrict__ Q, const u16* __restrict__ K,
                 const u16* __restrict__ V, u16* __restrict__ O) {
  const int qt = blockIdx.x, h = blockIdx.y, b = blockIdx.z;
  const int tid = threadIdx.x, lane = tid & 63, w = tid >> 6;
  const int r = lane & 15, g = lane >> 4;
  const int q0 = qt * 64;
  const int base = (b * 16 + h) * 131072;
  const u16* Qb = Q + base;
  const u16* Kb = K + base;
  const u16* Vb = V + base;

  __shared__ u16 Ks[64 * 64];
  __shared__ u16 Vt[64 * 64];
  __shared__ u16 Pl[4608];

  bf16x8 qf[2];
  {
    const u16* qp = Qb + (q0 + w * 16 + r) * 64 + g * 8;
    qf[0] = __builtin_bit_cast(bf16x8, *(const u16x8*)qp);
    qf[1] = __builtin_bit_cast(bf16x8, *(const u16x8*)(qp + 32));
  }

  f32x4 acc[4] = {};
  float m_run[4] = {-1e30f, -1e30f, -1e30f, -1e30f};
  float l_run[4] = {};

  const int nt = (qt <= 3) ? (qt + 1) : 4;
  const int srow = tid >> 3, sc = (tid & 7) * 8;

  for (int tix = 0; tix < nt; ++tix) {
    const int t = (tix == 0) ? 0 : ((qt <= 3) ? tix : (qt - 3 + tix));
    const int j0 = t * 64;
    __syncthreads();
#pragma unroll
    for (int i = 0; i < 2; ++i) {
      int row = i * 32 + srow;
      u16x8 kv = *(const u16x8*)(Kb + (j0 + row) * 64 + sc);
      *(u16x8*)((char*)Ks + swz(row, sc * 2)) = kv;
      u16x8 vv = *(const u16x8*)(Vb + (j0 + row) * 64 + sc);
#pragma unroll
      for (int qq = 0; qq < 8; ++qq) {
        int d = sc + qq;
        *(u16*)((char*)Vt + d * 128 + ((2 * row) ^ ((d & 7) << 4))) = vv[qq];
      }
    }
    __syncthreads();

    f32x4 S[4] = {};
#pragma unroll
    for (int kk = 0; kk < 2; ++kk)
#pragma unroll
      for (int n = 0; n < 4; ++n) {
        bf16x8 kf = __builtin_bit_cast(
            bf16x8,
            *(const u16x8*)((char*)Ks + swz(n * 16 + r, kk * 64 + g * 16)));
        S[n] = MFMA16(qf[kk], kf, S[n], 0, 0, 0);
      }

    float mloc[4] = {-1e30f, -1e30f, -1e30f, -1e30f};
#pragma unroll
    for (int n = 0; n < 4; ++n) {
      int j = j0 + n * 16 + r;
#pragma unroll
      for (int q = 0; q < 4; ++q) {
        int i = q0 + w * 16 + g * 4 + q;
        bool ok = (j <= i) && (((i - j) <= 128) || (j < 16));
        float s = ok ? S[n][q] * 0.125f : -1e30f;
        S[n][q] = s;
        mloc[q] = fmaxf(mloc[q], s);
      }
    }
#pragma unroll
    for (int q = 0; q < 4; ++q)
#pragma unroll
      for (int off = 1; off < 16; off <<= 1)
        mloc[q] = fmaxf(mloc[q], __shfl_xor(mloc[q], off));

    float alpha[4], rsum[4] = {};
#pragma unroll
    for (int q = 0; q < 4; ++q) {
      float mn = fmaxf(m_run[q], mloc[q]);
      alpha[q] = __expf(m_run[q] - mn);
      m_run[q] = mn;
    }
#pragma unroll
    for (int n = 0; n < 4; ++n)
#pragma unroll
      for (int q = 0; q < 4; ++q) {
        float p = __expf(S[n][q] - m_run[q]);
        S[n][q] = p;
        rsum[q] += p;
      }
#pragma unroll
    for (int q = 0; q < 4; ++q) {
#pragma unroll
      for (int off = 1; off < 16; off <<= 1)
        rsum[q] += __shfl_xor(rsum[q], off);
      l_run[q] = l_run[q] * alpha[q] + rsum[q];
    }
#pragma unroll
    for (int n = 0; n < 4; ++n) {
      acc[n][0] *= alpha[0];
      acc[n][1] *= alpha[1];
      acc[n][2] *= alpha[2];
      acc[n][3] *= alpha[3];
    }

#pragma unroll
    for (int n = 0; n < 4; ++n)
#pragma unroll
      for (int q = 0; q < 4; ++q)
        *((u16*)((char*)Pl + w * 2304 + (g * 4 + q) * 144) + (n * 16 + r)) =
            f2bf(S[n][q]);

#pragma unroll
    for (int kk = 0; kk < 2; ++kk) {
      bf16x8 pf = __builtin_bit_cast(
          bf16x8,
          *(const u16x8*)((char*)Pl + w * 2304 + r * 144 + kk * 64 + g * 16));
#pragma unroll
      for (int n = 0; n < 4; ++n) {
        bf16x8 vf = __builtin_bit_cast(
            bf16x8,
            *(const u16x8*)((char*)Vt + swz(n * 16 + r, kk * 64 + g * 16)));
        acc[n] = MFMA16(pf, vf, acc[n], 0, 0, 0);
      }
    }
  }

#pragma unroll
  for (int n = 0; n < 4; ++n)
#pragma unroll
    for (int q = 0; q < 4; ++q) {
      int s = q0 + w * 16 + g * 4 + q;
      int d = n * 16 + r;
      O[(b * 2048 + s) * 1024 + h * 64 + d] = f2bf(acc[n][q] / l_run[q]);
    }
}

// ---------------------------------------------------------------------------
extern "C" void kernel_launch(void* const* d_in, const int* in_sizes, int n_in,
                              void* d_out, int out_size, void* d_ws,
                              size_t ws_size, hipStream_t stream) {
  const float* b_q = (const float*)d_in[4];
  const float* b_k = (const float*)d_in[6];
  const float* b_v = (const float*)d_in[8];
  const float* b_o = (const float*)d_in[10];

  u16* ws = (u16*)d_ws;
  u16* Qw = ws + 16777216;
  u16* Kw = ws + 20971520;
  u16* Vw = ws + 25165824;
  u16* Aw = ws + 4194304;  // aliases Xq (dead after qkv projection)

  cast7<<<dim3(2048, 7), dim3(256), 0, stream>>>(
      (const float*)d_in[0], (const float*)d_in[1], (const float*)d_in[2],
      (const float*)d_in[3], (const float*)d_in[5], (const float*)d_in[7],
      (const float*)d_in[9], ws);
  qkv_gemm256<<<dim3(192), dim3(512), 0, stream>>>(ws, b_q, b_k, b_v, Qw, Kw,
                                                   Vw);
  attn_kernel<<<dim3(32, 16, 2), dim3(256), 0, stream>>>(Qw, Kw, Vw, Aw);
  out_gemm_p<<<dim3(256), dim3(256), 0, stream>>>(Aw, ws + 3145728, b_o,
                                                  (float*)d_out);
}

// Round 5
// 93.164 us; speedup vs baseline: 1.4762x; 1.0309x over previous
//
#include <hip/hip_runtime.h>

typedef unsigned short u16;
typedef u16 u16x8 __attribute__((ext_vector_type(8)));
typedef __bf16 bf16x8 __attribute__((ext_vector_type(8)));
typedef float f32x4 __attribute__((ext_vector_type(4)));

#define MFMA16 __builtin_amdgcn_mfma_f32_16x16x32_bf16

__device__ __forceinline__ u16 f2bf(float f) {
  unsigned u = __builtin_bit_cast(unsigned, f);
  u += 0x7FFFu + ((u >> 16) & 1u);
  return (u16)(u >> 16);
}

// XOR-swizzled LDS byte address for 64-bf16 (128B) rows (guide G4).
__device__ __forceinline__ int swz(int row, int bcol) {
  return row * 128 + (bcol ^ ((row & 7) << 4));
}

__device__ __forceinline__ void gl16(const u16* g, u16* l) {
  __builtin_amdgcn_global_load_lds(
      (const __attribute__((address_space(1))) unsigned int*)g,
      (__attribute__((address_space(3))) unsigned int*)l, 16, 0, 0);
}

// raw workgroup barrier (no vmcnt(0) drain)
__device__ __forceinline__ void BARR() {
  asm volatile("" ::: "memory");
  __builtin_amdgcn_s_barrier();
  asm volatile("" ::: "memory");
}
#define VMCNT(n) asm volatile("s_waitcnt vmcnt(" #n ")" ::: "memory")

// ---------------------------------------------------------------------------
// Flattened fp32 -> bf16 cast. 16M elements total, 8/thread, 8192 blocks.
// ws layout (u16): Wq 0 | Wk 1M | Wv 2M | Wo 3M | Xq 4M | Xk 8M | Xv 12M
// ---------------------------------------------------------------------------
__global__ __launch_bounds__(256)
void cast_all(const float* __restrict__ q, const float* __restrict__ k,
              const float* __restrict__ v, const float* __restrict__ wq,
              const float* __restrict__ wk, const float* __restrict__ wv,
              const float* __restrict__ wo, u16* __restrict__ ws) {
  const long i = ((long)blockIdx.x * 256 + threadIdx.x) * 8;
  const float* s;
  u16* d;
  if (i < 12582912) {  // X region (12M)
    const int seg = (int)(i >> 22);
    const float* xs = (seg == 0) ? q : (seg == 1) ? k : v;
    s = xs + (i & 4194303);
    d = ws + 4194304 + i;
  } else {  // weights (4M)
    const long j = i - 12582912;
    const int seg = (int)(j >> 20);
    const float* wsrc = (seg == 0) ? wq : (seg == 1) ? wk : (seg == 2) ? wv : wo;
    s = wsrc + (j & 1048575);
    d = ws + j;
  }
  float4 v0 = *(const float4*)s;
  float4 v1 = *(const float4*)(s + 4);
  u16x8 p = {f2bf(v0.x), f2bf(v0.y), f2bf(v0.z), f2bf(v0.w),
             f2bf(v1.x), f2bf(v1.y), f2bf(v1.z), f2bf(v1.w)};
  *(u16x8*)d = p;
}

// ---------------------------------------------------------------------------
// Shared 128x128 2-phase counted-vmcnt GEMM core. 4 waves, 64 KB LDS
// (2 blocks/CU resident -> cross-block wave overlap hides barrier stalls).
// A,B row-major bf16, ld=1024, K=1024 (16 K-tiles of 64).
//  ph1: STG B0,B1[t+1]->buf^1 | dsr A(8)+B-lo(4) | 16 MFMA | bar
//  ph2: STG A0,A1[t+2]->buf   | dsr B-hi(4)      | 16 MFMA | vmcnt(4) | bar
// Region-safety: staged region's last reader is >=1 barrier back; every dsr
// retires via the MFMA's lgkm wait before the phase barrier.
// ---------------------------------------------------------------------------
#define OSTGA(tt, c, j)                                                     \
  gl16(Ain + (m0 + (c)*64 + (w << 4) + (j)*8 + (lane >> 3)) * 1024 +        \
           (tt)*64 + (((lane & 7) ^ (lane >> 3)) << 3),                     \
       (u16*)(sb + (((tt)&1) << 15) + (c)*8192 + (w << 11) + ((j) << 10)))
#define OSTGB(tt, c, j)                                                     \
  gl16(W + (n0 + (c)*64 + (w << 4) + (j)*8 + (lane >> 3)) * 1024 +          \
           (tt)*64 + (((lane & 7) ^ (lane >> 3)) << 3),                     \
       (u16*)(sb + (((tt)&1) << 15) + 16384 + (c)*8192 + (w << 11) +        \
              ((j) << 10)))
#define OLDA()                                                              \
  _Pragma("unroll") for (int m = 0; m < 4; ++m) {                           \
    char* p = sb + bo + rowAb + m * 16 * 128;                               \
    af[0][m] = __builtin_bit_cast(bf16x8, *(const u16x8*)(p + colr0));      \
    af[1][m] = __builtin_bit_cast(bf16x8, *(const u16x8*)(p + colr1));      \
  }
#define OLDB(n)                                                             \
  {                                                                         \
    char* p = sb + bo + rowBb + (n)*16 * 128;                               \
    bf[0][n] = __builtin_bit_cast(bf16x8, *(const u16x8*)(p + colr0));      \
    bf[1][n] = __builtin_bit_cast(bf16x8, *(const u16x8*)(p + colr1));      \
  }
#define OFMA(nh)                                                            \
  __builtin_amdgcn_s_setprio(1);                                            \
  _Pragma("unroll") for (int m = 0; m < 4; ++m)                             \
  _Pragma("unroll") for (int n = 0; n < 2; ++n) {                           \
    acc[m][(nh)*2 + n] =                                                    \
        MFMA16(af[0][m], bf[0][(nh)*2 + n], acc[m][(nh)*2 + n], 0, 0, 0);   \
    acc[m][(nh)*2 + n] =                                                    \
        MFMA16(af[1][m], bf[1][(nh)*2 + n], acc[m][(nh)*2 + n], 0, 0, 0);   \
  }                                                                         \
  __builtin_amdgcn_s_setprio(0);

__device__ __forceinline__ void core128(const u16* __restrict__ Ain,
                                        const u16* __restrict__ W, int m0,
                                        int n0, char* sb,
                                        f32x4 (&acc)[4][4]) {
  const int tid = threadIdx.x, lane = tid & 63, w = tid >> 6;
  const int wm = w >> 1, wn = w & 1;
  const int r = lane & 15, g = lane >> 4;
  bf16x8 af[2][4], bf[2][4];

  const int colr0 = (g * 16) ^ ((r & 7) << 4);
  const int colr1 = (64 + g * 16) ^ ((r & 7) << 4);
  const int rowAb = (wm * 64 + r) * 128;
  const int rowBb = 16384 + (wn * 64 + r) * 128;

  // prologue: A[0], B[0], A[1]; leave A[1] (4 newest) in flight
#pragma unroll
  for (int c = 0; c < 2; ++c) { OSTGA(0, c, 0); OSTGA(0, c, 1); }
#pragma unroll
  for (int c = 0; c < 2; ++c) { OSTGB(0, c, 0); OSTGB(0, c, 1); }
#pragma unroll
  for (int c = 0; c < 2; ++c) { OSTGA(1, c, 0); OSTGA(1, c, 1); }
  VMCNT(4);
  __builtin_amdgcn_s_barrier();
  asm volatile("" ::: "memory");

  for (int t = 0; t < 16; ++t) {
    const int bo = (t & 1) << 15;
    // ---- phase 1
    if (t < 15) { OSTGB(t + 1, 0, 0); OSTGB(t + 1, 0, 1); OSTGB(t + 1, 1, 0); OSTGB(t + 1, 1, 1); }
    OLDA();
    OLDB(0); OLDB(1);
    OFMA(0);
    BARR();
    // ---- phase 2
    if (t < 14) { OSTGA(t + 2, 0, 0); OSTGA(t + 2, 0, 1); OSTGA(t + 2, 1, 0); OSTGA(t + 2, 1, 1); }
    OLDB(2); OLDB(3);
    OFMA(1);
    if (t < 14) { VMCNT(4); } else if (t == 14) { VMCNT(0); }
    BARR();
  }
}

// ---------------------------------------------------------------------------
// QKV projection: 768 blocks (3 z * 32 m * 8 n), 128x128 tile, 2 blocks/CU.
// ---------------------------------------------------------------------------
__global__ __launch_bounds__(256)
void qkv_gemm128(const u16* __restrict__ ws_in, const float* __restrict__ c0,
                 const float* __restrict__ c1, const float* __restrict__ c2,
                 u16* __restrict__ o0, u16* __restrict__ o1,
                 u16* __restrict__ o2) {
  const int bid = blockIdx.x;
  const int s = (bid & 7) * 96 + (bid >> 3);  // XCD-contiguous, 768 % 8 == 0
  const int z = s >> 8;
  const int rem = s & 255;
  const int m0 = (rem >> 3) << 7, n0 = (rem & 7) << 7;

  const u16* __restrict__ Ain = ws_in + 4194304 + z * 4194304;
  const u16* __restrict__ W = ws_in + z * 1048576;
  const float* Bi = (z == 0) ? c0 : (z == 1) ? c1 : c2;
  u16* O = (z == 0) ? o0 : (z == 1) ? o1 : o2;

  const int tid = threadIdx.x, lane = tid & 63, w = tid >> 6;
  const int wm = w >> 1, wn = w & 1;
  const int r = lane & 15, g = lane >> 4;

  __shared__ u16 SH[32768];  // 64 KB
  f32x4 acc[4][4] = {};
  core128(Ain, W, m0, n0, (char*)SH, acc);

  // epilogue -> bf16 [B,H,S,64]; C/D layout col=lane&15, row=g*4+q
#pragma unroll
  for (int n = 0; n < 4; ++n) {
    const int gn = n0 + wn * 64 + n * 16 + r;
    const int hh = gn >> 6, d = gn & 63;
    const float bv = Bi[gn];
#pragma unroll
    for (int m = 0; m < 4; ++m) {
#pragma unroll
      for (int q = 0; q < 4; ++q) {
        int gm = m0 + wm * 64 + m * 16 + g * 4 + q;
        int bb = gm >> 11, sIdx = gm & 2047;
        O[((bb * 16 + hh) * 2048 + sIdx) * 64 + d] = f2bf(acc[m][n][q] + bv);
      }
    }
  }
}

// ---------------------------------------------------------------------------
// Output projection: 256 blocks, 128x128 tile, fp32 out.
// ---------------------------------------------------------------------------
__global__ __launch_bounds__(256)
void out_gemm_p(const u16* __restrict__ Ain2, const u16* __restrict__ W2,
                const float* __restrict__ Bi, float* __restrict__ C) {
  const int bid = blockIdx.x;
  const int s = (bid & 7) * 32 + (bid >> 3);  // 256 % 8 == 0
  const int m0 = (s >> 3) << 7, n0 = (s & 7) << 7;

  const int tid = threadIdx.x, lane = tid & 63, w = tid >> 6;
  const int wm = w >> 1, wn = w & 1;
  const int r = lane & 15, g = lane >> 4;

  __shared__ u16 SH[32768];  // 64 KB
  f32x4 acc[4][4] = {};
  core128(Ain2, W2, m0, n0, (char*)SH, acc);

#pragma unroll
  for (int m = 0; m < 4; ++m) {
#pragma unroll
    for (int n = 0; n < 4; ++n) {
      int gn = n0 + wn * 64 + n * 16 + r;
      float bv = Bi[gn];
#pragma unroll
      for (int q = 0; q < 4; ++q) {
        int gm = m0 + wm * 64 + m * 16 + g * 4 + q;
        C[gm * 1024 + gn] = acc[m][n][q] + bv;
      }
    }
  }
}

// ---------------------------------------------------------------------------
// Sparse flash attention (unchanged). grid (32, 16, 2), 256 threads.
// ---------------------------------------------------------------------------
__global__ __launch_bounds__(256)
void attn_kernel(const u16* __restrict__ Q, const u16* __restrict__ K,
                 const u16* __restrict__ V, u16* __restrict__ O) {
  const int qt = blockIdx.x, h = blockIdx.y, b = blockIdx.z;
  const int tid = threadIdx.x, lane = tid & 63, w = tid >> 6;
  const int r = lane & 15, g = lane >> 4;
  const int q0 = qt * 64;
  const int base = (b * 16 + h) * 131072;
  const u16* Qb = Q + base;
  const u16* Kb = K + base;
  const u16* Vb = V + base;

  __shared__ u16 Ks[64 * 64];
  __shared__ u16 Vt[64 * 64];
  __shared__ u16 Pl[4608];

  bf16x8 qf[2];
  {
    const u16* qp = Qb + (q0 + w * 16 + r) * 64 + g * 8;
    qf[0] = __builtin_bit_cast(bf16x8, *(const u16x8*)qp);
    qf[1] = __builtin_bit_cast(bf16x8, *(const u16x8*)(qp + 32));
  }

  f32x4 acc[4] = {};
  float m_run[4] = {-1e30f, -1e30f, -1e30f, -1e30f};
  float l_run[4] = {};

  const int nt = (qt <= 3) ? (qt + 1) : 4;
  const int srow = tid >> 3, sc = (tid & 7) * 8;

  for (int tix = 0; tix < nt; ++tix) {
    const int t = (tix == 0) ? 0 : ((qt <= 3) ? tix : (qt - 3 + tix));
    const int j0 = t * 64;
    __syncthreads();
#pragma unroll
    for (int i = 0; i < 2; ++i) {
      int row = i * 32 + srow;
      u16x8 kv = *(const u16x8*)(Kb + (j0 + row) * 64 + sc);
      *(u16x8*)((char*)Ks + swz(row, sc * 2)) = kv;
      u16x8 vv = *(const u16x8*)(Vb + (j0 + row) * 64 + sc);
#pragma unroll
      for (int qq = 0; qq < 8; ++qq) {
        int d = sc + qq;
        *(u16*)((char*)Vt + d * 128 + ((2 * row) ^ ((d & 7) << 4))) = vv[qq];
      }
    }
    __syncthreads();

    f32x4 S[4] = {};
#pragma unroll
    for (int kk = 0; kk < 2; ++kk)
#pragma unroll
      for (int n = 0; n < 4; ++n) {
        bf16x8 kf = __builtin_bit_cast(
            bf16x8,
            *(const u16x8*)((char*)Ks + swz(n * 16 + r, kk * 64 + g * 16)));
        S[n] = MFMA16(qf[kk], kf, S[n], 0, 0, 0);
      }

    float mloc[4] = {-1e30f, -1e30f, -1e30f, -1e30f};
#pragma unroll
    for (int n = 0; n < 4; ++n) {
      int j = j0 + n * 16 + r;
#pragma unroll
      for (int q = 0; q < 4; ++q) {
        int i = q0 + w * 16 + g * 4 + q;
        bool ok = (j <= i) && (((i - j) <= 128) || (j < 16));
        float s = ok ? S[n][q] * 0.125f : -1e30f;
        S[n][q] = s;
        mloc[q] = fmaxf(mloc[q], s);
      }
    }
#pragma unroll
    for (int q = 0; q < 4; ++q)
#pragma unroll
      for (int off = 1; off < 16; off <<= 1)
        mloc[q] = fmaxf(mloc[q], __shfl_xor(mloc[q], off));

    float alpha[4], rsum[4] = {};
#pragma unroll
    for (int q = 0; q < 4; ++q) {
      float mn = fmaxf(m_run[q], mloc[q]);
      alpha[q] = __expf(m_run[q] - mn);
      m_run[q] = mn;
    }
#pragma unroll
    for (int n = 0; n < 4; ++n)
#pragma unroll
      for (int q = 0; q < 4; ++q) {
        float p = __expf(S[n][q] - m_run[q]);
        S[n][q] = p;
        rsum[q] += p;
      }
#pragma unroll
    for (int q = 0; q < 4; ++q) {
#pragma unroll
      for (int off = 1; off < 16; off <<= 1)
        rsum[q] += __shfl_xor(rsum[q], off);
      l_run[q] = l_run[q] * alpha[q] + rsum[q];
    }
#pragma unroll
    for (int n = 0; n < 4; ++n) {
      acc[n][0] *= alpha[0];
      acc[n][1] *= alpha[1];
      acc[n][2] *= alpha[2];
      acc[n][3] *= alpha[3];
    }

#pragma unroll
    for (int n = 0; n < 4; ++n)
#pragma unroll
      for (int q = 0; q < 4; ++q)
        *((u16*)((char*)Pl + w * 2304 + (g * 4 + q) * 144) + (n * 16 + r)) =
            f2bf(S[n][q]);

#pragma unroll
    for (int kk = 0; kk < 2; ++kk) {
      bf16x8 pf = __builtin_bit_cast(
          bf16x8,
          *(const u16x8*)((char*)Pl + w * 2304 + r * 144 + kk * 64 + g * 16));
#pragma unroll
      for (int n = 0; n < 4; ++n) {
        bf16x8 vf = __builtin_bit_cast(
            bf16x8,
            *(const u16x8*)((char*)Vt + swz(n * 16 + r, kk * 64 + g * 16)));
        acc[n] = MFMA16(pf, vf, acc[n], 0, 0, 0);
      }
    }
  }

#pragma unroll
  for (int n = 0; n < 4; ++n)
#pragma unroll
    for (int q = 0; q < 4; ++q) {
      int s = q0 + w * 16 + g * 4 + q;
      int d = n * 16 + r;
      O[(b * 2048 + s) * 1024 + h * 64 + d] = f2bf(acc[n][q] / l_run[q]);
    }
}

// ---------------------------------------------------------------------------
extern "C" void kernel_launch(void* const* d_in, const int* in_sizes, int n_in,
                              void* d_out, int out_size, void* d_ws,
                              size_t ws_size, hipStream_t stream) {
  const float* b_q = (const float*)d_in[4];
  const float* b_k = (const float*)d_in[6];
  const float* b_v = (const float*)d_in[8];
  const float* b_o = (const float*)d_in[10];

  u16* ws = (u16*)d_ws;
  u16* Qw = ws + 16777216;
  u16* Kw = ws + 20971520;
  u16* Vw = ws + 25165824;
  u16* Aw = ws + 4194304;  // aliases Xq (dead after qkv projection)

  cast_all<<<dim3(8192), dim3(256), 0, stream>>>(
      (const float*)d_in[0], (const float*)d_in[1], (const float*)d_in[2],
      (const float*)d_in[3], (const float*)d_in[5], (const float*)d_in[7],
      (const float*)d_in[9], ws);
  qkv_gemm128<<<dim3(768), dim3(256), 0, stream>>>(ws, b_q, b_k, b_v, Qw, Kw,
                                                   Vw);
  attn_kernel<<<dim3(32, 16, 2), dim3(256), 0, stream>>>(Qw, Kw, Vw, Aw);
  out_gemm_p<<<dim3(256), dim3(256), 0, stream>>>(Aw, ws + 3145728, b_o,
                                                  (float*)d_out);
}